// Round 3
// baseline (217.895 us; speedup 1.0000x reference)
//
#include <hip/hip_runtime.h>
#include <math.h>

#define N_NODES 100000
#define DIMS 128
#define RS 136   // W16 LDS row stride in halves (272 B): balanced-bank b128 reads
#define CS 136   // epilogue LDS row stride in halves

typedef _Float16 f16_t;
typedef f16_t half4 __attribute__((ext_vector_type(4)));
typedef f16_t half2_t __attribute__((ext_vector_type(2)));
typedef f16_t f16x8 __attribute__((ext_vector_type(8)));
typedef float f32x4 __attribute__((ext_vector_type(4)));

__device__ __forceinline__ f16x8 cvt8(float4 a, float4 b) {
    f16x8 h = { (f16_t)a.x, (f16_t)a.y, (f16_t)a.z, (f16_t)a.w,
                (f16_t)b.x, (f16_t)b.y, (f16_t)b.z, (f16_t)b.w };
    return h;
}

// wz16 = (fp16)(z @ W^T + b), z16 = (fp16)z, via mfma_f32_16x16x32_f16.
// R3: W staged ONCE per 256 output rows (4 strips/wave) -> 391 blocks,
// W-read traffic 100 MB -> 25 MB; wave-private cl epilogue reused per strip
// (same-wave DS ops ordered, no barrier needed between strips).
__global__ __launch_bounds__(256, 2)
void wz_kernel(const float* __restrict__ z, const float* __restrict__ W,
               const float* __restrict__ b,
               f16_t* __restrict__ z16, f16_t* __restrict__ wz16) {
    __shared__ f16_t wl[DIMS * RS];     // 34816 B
    __shared__ f16_t cl[4][16 * CS];    // 17408 B  (52.2 KB total)
    const int t    = threadIdx.x;
    const int lane = t & 63;
    const int wave = t >> 6;
    const int m    = lane & 15;
    const int quad = lane >> 4;

    // Stage W -> fp16 LDS: 128x128 = 4096 float4 chunks, 16 per thread.
    #pragma unroll
    for (int it = 0; it < 16; ++it) {
        int f  = it * 256 + t;
        int r  = f >> 5;             // W row (output col) 0..127
        int i4 = (f & 31) << 2;      // k offset 0..124
        float4 v = *(const float4*)(W + r * DIMS + i4);
        half4 h = { (f16_t)v.x, (f16_t)v.y, (f16_t)v.z, (f16_t)v.w };
        *(half4*)(wl + r * RS + i4) = h;
    }
    __syncthreads();

    f16_t* my = cl[wave];

    for (int s = 0; s < 4; ++s) {
        const int r0    = blockIdx.x * 256 + s * 64 + wave * 16;
        const int arow  = r0 + m;
        const int garow = arow < N_NODES ? arow : N_NODES - 1;   // clamp loads

        // A-frags for K=128 (4 chunks of 32), fused z16 emission.
        f16x8 afrag[4];
        #pragma unroll
        for (int c = 0; c < 4; ++c) {
            const int k0 = c * 32 + quad * 8;
            float4 v0 = *(const float4*)(z + (size_t)garow * DIMS + k0);
            float4 v1 = *(const float4*)(z + (size_t)garow * DIMS + k0 + 4);
            afrag[c] = cvt8(v0, v1);
            if (arow < N_NODES)
                *(f16x8*)(z16 + (size_t)arow * DIMS + k0) = afrag[c];
        }

        // 8 column tiles x 4 k-chunks of MFMA; B-frags from LDS.
        f32x4 acc[8];
        #pragma unroll
        for (int nt = 0; nt < 8; ++nt) acc[nt] = (f32x4){0.f, 0.f, 0.f, 0.f};

        #pragma unroll
        for (int nt = 0; nt < 8; ++nt) {
            #pragma unroll
            for (int c = 0; c < 4; ++c) {
                f16x8 bfrag = *(const f16x8*)(wl + (nt * 16 + m) * RS + c * 32 + quad * 8);
                acc[nt] = __builtin_amdgcn_mfma_f32_16x16x32_f16(afrag[c], bfrag, acc[nt], 0, 0, 0);
            }
        }

        // Epilogue: bias + cvt -> wave-local LDS transpose -> coalesced stores.
        #pragma unroll
        for (int nt = 0; nt < 8; ++nt) {
            const float bv = b[nt * 16 + m];
            #pragma unroll
            for (int r = 0; r < 4; ++r)
                my[(quad * 4 + r) * CS + nt * 16 + m] = (f16_t)(acc[nt][r] + bv);
        }
        #pragma unroll
        for (int p = 0; p < 4; ++p) {
            const int rr = p * 4 + (lane >> 4);
            const int cc = (lane & 15) * 8;
            const int gr = r0 + rr;
            if (gr < N_NODES)
                *(f16x8*)(wz16 + (size_t)gr * DIMS + cc) = *(const f16x8*)(my + rr * CS + cc);
        }
    }
}

// Edge kernel v4: 16 edges/wave, 16 lanes/edge, 16 B/lane gathers.
// launch_bounds(256,2) relaxes the VGPR cap (v3 regression: regalloc chose
// 20 VGPR -> only ~2 loads in flight). 8 NAMED f16x8 destinations + hoisted
// uniform index s_loads force a true 8-deep load batch (8 KB/wave in flight).
__global__ __launch_bounds__(256, 2)
void edge_kernel(const f16_t* __restrict__ z16, const f16_t* __restrict__ wz16,
                 const int* __restrict__ src, const int* __restrict__ dst,
                 float* __restrict__ out, int E) {
    const int wid = blockIdx.x * 4 + (threadIdx.x >> 6);   // wave id
    const int l   = threadIdx.x & 63;
    const int q   = l >> 4;        // edge slot within round (0..3)
    const int ls  = l & 15;        // lane within edge group
    const int e0  = __builtin_amdgcn_readfirstlane(wid << 4);   // 16 edges/wave
    if (e0 >= E) return;

    // Uniform index loads -> s_load_dwordx4 x8, all hoisted.
    const int4 s0 = *(const int4*)(src + e0);
    const int4 s1 = *(const int4*)(src + e0 + 4);
    const int4 s2 = *(const int4*)(src + e0 + 8);
    const int4 s3 = *(const int4*)(src + e0 + 12);
    const int4 d0 = *(const int4*)(dst + e0);
    const int4 d1 = *(const int4*)(dst + e0 + 4);
    const int4 d2 = *(const int4*)(dst + e0 + 8);
    const int4 d3 = *(const int4*)(dst + e0 + 12);

    const unsigned lo = (unsigned)ls << 4;   // byte offset within 256-B row

#define SEL(v4) (q == 0 ? (v4).x : q == 1 ? (v4).y : q == 2 ? (v4).z : (v4).w)
#define GATHER(tbl, idx) (*(const f16x8*)((const char*)(tbl) + (((unsigned)(idx) << 8) | lo)))

    // Batch-issue all 8 gathers into NAMED registers (no array -> no scratch,
    // no regalloc collapse).
    f16x8 a0 = GATHER(z16,  SEL(s0));
    f16x8 w0 = GATHER(wz16, SEL(d0));
    f16x8 a1 = GATHER(z16,  SEL(s1));
    f16x8 w1 = GATHER(wz16, SEL(d1));
    f16x8 a2 = GATHER(z16,  SEL(s2));
    f16x8 w2 = GATHER(wz16, SEL(d2));
    f16x8 a3 = GATHER(z16,  SEL(s3));
    f16x8 w3 = GATHER(wz16, SEL(d3));

#if __has_builtin(__builtin_amdgcn_fdot2)
#define DOT8(p, A, Wv)                                                  \
    {                                                                   \
        const half2_t* ah = (const half2_t*)&(A);                       \
        const half2_t* wh = (const half2_t*)&(Wv);                      \
        p = __builtin_amdgcn_fdot2(ah[0], wh[0], p, false);             \
        p = __builtin_amdgcn_fdot2(ah[1], wh[1], p, false);             \
        p = __builtin_amdgcn_fdot2(ah[2], wh[2], p, false);             \
        p = __builtin_amdgcn_fdot2(ah[3], wh[3], p, false);             \
    }
#else
#define DOT8(p, A, Wv)                                                  \
    {                                                                   \
        _Pragma("unroll")                                               \
        for (int i = 0; i < 8; ++i)                                     \
            p = fmaf((float)(A)[i], (float)(Wv)[i], p);                 \
    }
#endif

#define FINISH(A, Wv, r)                                                \
    {                                                                   \
        float p = 0.0f;                                                 \
        DOT8(p, A, Wv);                                                 \
        p += __shfl_xor(p, 8);                                          \
        p += __shfl_xor(p, 4);                                          \
        p += __shfl_xor(p, 2);                                          \
        p += __shfl_xor(p, 1);                                          \
        if (ls == 0)                                                    \
            out[e0 + (r) * 4 + q] = 1.0f / (1.0f + __expf(-p));         \
    }

    FINISH(a0, w0, 0);
    FINISH(a1, w1, 1);
    FINISH(a2, w2, 2);
    FINISH(a3, w3, 3);

#undef SEL
#undef GATHER
#undef DOT8
#undef FINISH
}

extern "C" void kernel_launch(void* const* d_in, const int* in_sizes, int n_in,
                              void* d_out, int out_size, void* d_ws, size_t ws_size,
                              hipStream_t stream) {
    const float* z  = (const float*)d_in[0];
    const int*   ei = (const int*)d_in[1];   // [2, E] int32
    const float* W  = (const float*)d_in[2];
    const float* b  = (const float*)d_in[3];
    float* out = (float*)d_out;

    const int E = in_sizes[1] / 2;

    f16_t* z16  = (f16_t*)d_ws;                                       // 25.6 MB
    f16_t* wz16 = (f16_t*)((char*)d_ws + (size_t)N_NODES * DIMS * 2); // 25.6 MB

    const int row_blocks = (N_NODES + 255) / 256;   // 391
    wz_kernel<<<row_blocks, 256, 0, stream>>>(z, W, b, z16, wz16);

    const int waves  = (E + 15) / 16;               // 16 edges per wave
    const int blocks = (waves + 3) / 4;             // 4 waves per block
    edge_kernel<<<blocks, 256, 0, stream>>>(z16, wz16, ei, ei + E, out, E);
}